// Round 1
// baseline (371.150 us; speedup 1.0000x reference)
//
#include <hip/hip_runtime.h>
#include <stdint.h>

#define NB 64
#define NH 512
#define NW 512
#define RPAD 10
#define NROWS (NH + 2 * RPAD)          // 532 padded rows
#define RWORDS 18                      // u32 words per padded row (bit i == x = i-32)
#define IMG_WORDS (NROWS * RWORDS)     // 9576 words / image
#define NPIX (NH * NW)

// ---------------- kernel A: build padded foreground bitmask ----------------
// Layout: bit position i within a row corresponds to pixel x = i - 32.
// Image bits occupy bit 32..543 (words 1..16); words 0 and 17 are zero pad.
// Rows 0..9 and 522..531 are zero pad (y = r - 10).
__global__ __launch_bounds__(256) void build_bits(const float* __restrict__ targ,
                                                  uint32_t* __restrict__ bits) {
    const int r = blockIdx.x;   // padded row 0..531
    const int b = blockIdx.y;   // image
    const int tid = threadIdx.x;
    const int wave = tid >> 6, lane = tid & 63;
    uint32_t* row = bits + (size_t)b * IMG_WORDS + (size_t)r * RWORDS;
    const int y = r - RPAD;
    const bool inrow = (y >= 0) && (y < NH);

#pragma unroll
    for (int it = 0; it < 2; ++it) {
        const int x = it * 256 + wave * 64 + lane;
        float tv = 0.0f;
        if (inrow) tv = targ[((size_t)b * NH + y) * NW + x];
        unsigned long long m = __ballot(tv > 0.5f);
        if (lane == 0) {
            const int w1 = it * 8 + wave * 2 + 1;   // bits start at 64*chunk + 32
            row[w1]     = (uint32_t)m;
            row[w1 + 1] = (uint32_t)(m >> 32);
        }
    }
    if (tid == 0) row[0] = 0;
    else if (tid == 1) row[RWORDS - 1] = 0;
}

// ---------------- kernel B: fused per-pixel loss + distance transform ----------------
// Per-sample partials (8 floats):
// 0: sum pc*t   1: sum pc   2: sum t   3: sum bce(logits)
// 4: sum dist*|pc-tb|   5: fg count   6: sum_fg bce_p   7: sum_bg bce_p
__global__ __launch_bounds__(256) void main_loss(const float* __restrict__ pred,
                                                 const float* __restrict__ targ,
                                                 const uint32_t* __restrict__ bits,
                                                 float* __restrict__ partials) {
    const int tile = blockIdx.x;   // 0..1  (256 px each)
    const int y    = blockIdx.y;   // 0..511
    const int b    = blockIdx.z;   // image
    const int tid  = threadIdx.x;
    const int x0   = tile * 256;
    const int x    = x0 + tid;

    // stage 21 bitmask rows x 10 words into LDS
    __shared__ uint32_t lrow[21][10];
    const int w0 = (x0 + 22) >> 5;
    const uint32_t* img = bits + (size_t)b * IMG_WORDS;
    if (tid < 210) {
        const int rr = tid / 10, lw = tid % 10;
        lrow[rr][lw] = img[(size_t)(y + rr) * RWORDS + (w0 + lw)];
    }
    __syncthreads();

    const size_t idx = ((size_t)b * NH + y) * NW + x;
    const float xv = pred[idx];
    const float tv = targ[idx];

    // ---- distance transform: min over disc offsets of dy^2+dx^2 ----
    // window bit j (0..20) == dx = j-10. Disc masks per dy, |dx| <= floor(sqrt(100-dy^2)).
    static const uint32_t DMASK[21] = {
        0x400u,   0x7FC0u,  0x1FFF0u, 0x3FFF8u, 0x7FFFCu, 0x7FFFCu, 0xFFFFEu,
        0xFFFFEu, 0xFFFFEu, 0xFFFFEu, 0x1FFFFFu,0xFFFFEu, 0xFFFFEu, 0xFFFFEu,
        0xFFFFEu, 0x7FFFCu, 0x7FFFCu, 0x3FFF8u, 0x1FFF0u, 0x7FC0u,  0x400u };
    static const int DY2[21] = {100,81,64,49,36,25,16,9,4,1,0,1,4,9,16,25,36,49,64,81,100};

    const int s  = (x + 22) & 31;
    const int lw = ((x + 22) >> 5) - w0;
    int mind2 = 1 << 20;
#pragma unroll
    for (int r = 0; r < 21; ++r) {
        const uint64_t v = (uint64_t)lrow[r][lw] | ((uint64_t)lrow[r][lw + 1] << 32);
        const uint32_t win = (uint32_t)(v >> s) & DMASK[r];
        // fold: c bit k set => some dx with |dx| = k present. sentinel 0x400 => |dx|=10
        // (fake d2 = dy2+100 > 100 for dy!=0; == 100 for dy==0 -> dist 10 == clamp). safe.
        const uint32_t c = (win >> 10) | (__builtin_bitreverse32(win) >> 21) | 0x400u;
        const int dx = __builtin_ctz(c);
        const int d2 = DY2[r] + dx * dx;
        mind2 = min(mind2, d2);
    }
    const float dist = (mind2 > 100) ? 10.0f : __fsqrt_rn((float)mind2);

    // ---- per-pixel loss terms ----
    const float p  = 1.0f / (1.0f + __expf(-xv));
    const float pc = fminf(fmaxf(p, 1e-7f), 1.0f - 1e-7f);
    const float tb = (tv > 0.5f) ? 1.0f : 0.0f;
    const float bce  = fmaxf(xv, 0.0f) - xv * tv + __logf(1.0f + __expf(-fabsf(xv)));
    const float bdry = dist * fabsf(pc - tb);
    const float bce_p = -(tv * __logf(pc) + (1.0f - tv) * __logf(1.0f - pc));

    float vals[8];
    vals[0] = pc * tv;
    vals[1] = pc;
    vals[2] = tv;
    vals[3] = bce;
    vals[4] = bdry;
    vals[5] = tb;
    vals[6] = tb * bce_p;
    vals[7] = (1.0f - tb) * bce_p;

    // ---- block reduction: wave shuffle -> LDS -> 8 atomics/block ----
    const int lane = tid & 63, wave = tid >> 6;
#pragma unroll
    for (int k = 0; k < 8; ++k) {
#pragma unroll
        for (int off = 32; off > 0; off >>= 1)
            vals[k] += __shfl_down(vals[k], off, 64);
    }
    __shared__ float red[4][8];
    if (lane == 0) {
#pragma unroll
        for (int k = 0; k < 8; ++k) red[wave][k] = vals[k];
    }
    __syncthreads();
    if (tid < 8) {
        const float sum = red[0][tid] + red[1][tid] + red[2][tid] + red[3][tid];
        atomicAdd(&partials[b * 8 + tid], sum);
    }
}

// ---------------- kernel C: per-sample combine + batch mean ----------------
__global__ __launch_bounds__(64) void finalize(const float* __restrict__ partials,
                                               const int* __restrict__ task_ids,
                                               float* __restrict__ out) {
    const int b = threadIdx.x;  // 64 samples, one wave
    const float Nf = (float)NPIX;
    const float inter = partials[b * 8 + 0];
    const float spc   = partials[b * 8 + 1];
    const float st    = partials[b * 8 + 2];
    const float sbce  = partials[b * 8 + 3];
    const float sbdry = partials[b * 8 + 4];
    const float sfg   = partials[b * 8 + 5];
    const float sfgb  = partials[b * 8 + 6];
    const float sbgb  = partials[b * 8 + 7];

    const float dice = 1.0f - (2.0f * inter + 1e-5f) / (spc + st + 1e-5f);
    const float base = dice + sbce / Nf;
    const float bdry = sbdry / Nf;
    const float bgc  = Nf - sfg;
    const float fgw  = fminf(fmaxf(bgc / (sfg + 1e-7f), 1.0f), 10.0f);
    float fgl = (fgw * sfgb + sbgb) / Nf;
    if (sfg == 0.0f) fgl = 0.0f;

    const int t = task_ids[b];
    const float BW[3]  = {1.0f, 1.0f, 1.0f};
    const float BDW[3] = {2.0f, 3.0f, 5.0f};
    const float FW[3]  = {1.0f, 1.5f, 3.0f};
    float per = BW[t] * base + BDW[t] * bdry + FW[t] * fgl;

#pragma unroll
    for (int off = 32; off > 0; off >>= 1)
        per += __shfl_down(per, off, 64);
    if (b == 0) out[0] = per * (1.0f / 64.0f);
}

extern "C" void kernel_launch(void* const* d_in, const int* in_sizes, int n_in,
                              void* d_out, int out_size, void* d_ws, size_t ws_size,
                              hipStream_t stream) {
    const float* pred     = (const float*)d_in[0];
    const float* targ     = (const float*)d_in[1];
    const int*   task_ids = (const int*)d_in[2];
    float* out = (float*)d_out;

    // ws layout: [0,2KB) per-sample partials, [4KB, 4KB+2.45MB) bitmask
    float* partials = (float*)d_ws;
    uint32_t* bits = (uint32_t*)((char*)d_ws + 4096);

    hipMemsetAsync(partials, 0, NB * 8 * sizeof(float), stream);
    build_bits<<<dim3(NROWS, NB), 256, 0, stream>>>(targ, bits);
    main_loss<<<dim3(NW / 256, NH, NB), 256, 0, stream>>>(pred, targ, bits, partials);
    finalize<<<1, 64, 0, stream>>>(partials, task_ids, out);
}

// Round 2
// 167.924 us; speedup vs baseline: 2.2102x; 2.2102x over previous
//
#include <hip/hip_runtime.h>
#include <stdint.h>

#define NB 64
#define NH 512
#define NW 512
#define RPAD 10
#define NROWS (NH + 2 * RPAD)          // 532 padded rows
#define RWORDS 18                      // u32 words per padded row (bit i == x = i-32)
#define IMG_WORDS (NROWS * RWORDS)     // 9576 words / image
#define NPIX (NH * NW)

#if __has_builtin(__builtin_amdgcn_alignbit)
#define ALIGNBIT(hi, lo, s) __builtin_amdgcn_alignbit((hi), (lo), (s))
#else
#define ALIGNBIT(hi, lo, s) ((uint32_t)(((((uint64_t)(hi)) << 32) | (lo)) >> ((s) & 31)))
#endif

// ---------------- kernel A: build padded foreground bitmask ----------------
// bit i of a padded row == pixel x = i-32; image bits live in words 1..16.
// Words 0,17 and pad rows are zeroed by the memset in kernel_launch.
__global__ __launch_bounds__(256) void build_bits(const float* __restrict__ targ,
                                                  uint32_t* __restrict__ bits) {
    const int y0 = blockIdx.x * 4;          // 4 image rows per block
    const int b  = blockIdx.y;
    const int tid = threadIdx.x;
    const int ry = y0 + (tid >> 6);         // image row for this thread
    const int xb = (tid & 63) * 8;          // 8 px per thread

    const float4* tg = (const float4*)(targ + ((size_t)b * NH + ry) * NW + xb);
    const float4 a = tg[0];
    const float4 c = tg[1];
    uint32_t m = (uint32_t)(a.x > 0.5f)
               | ((uint32_t)(a.y > 0.5f) << 1)
               | ((uint32_t)(a.z > 0.5f) << 2)
               | ((uint32_t)(a.w > 0.5f) << 3)
               | ((uint32_t)(c.x > 0.5f) << 4)
               | ((uint32_t)(c.y > 0.5f) << 5)
               | ((uint32_t)(c.z > 0.5f) << 6)
               | ((uint32_t)(c.w > 0.5f) << 7);

    __shared__ uint32_t swd[64];            // 4 rows x 16 words, byte-packed
    ((uint8_t*)swd)[tid] = (uint8_t)m;
    __syncthreads();
    if (tid < 64) {
        const int rw = tid >> 4, ww = tid & 15;
        bits[(size_t)b * IMG_WORDS + (size_t)(y0 + rw + RPAD) * RWORDS + 1 + ww] = swd[tid];
    }
}

// ---------------- kernel B: fused per-pixel loss + distance transform ----------------
// Per-sample partials (8 floats):
// 0: sum pc*t  1: sum pc  2: sum t  3: sum bce(logits)
// 4: sum dist*|pc-tb|  5: fg count  6: sum_fg bce_p  7: sum_bg bce_p
__global__ __launch_bounds__(256) void main_loss(const float* __restrict__ pred,
                                                 const float* __restrict__ targ,
                                                 const uint32_t* __restrict__ bits,
                                                 float* __restrict__ partials) {
    const int y0 = blockIdx.x * 4;          // 4 rows per block, one per wave
    const int b  = blockIdx.y;
    const int tid  = threadIdx.x;
    const int wave = tid >> 6, lane = tid & 63;
    const int y = y0 + wave;
    const int x = lane * 8;                 // 8 px per thread

    // stage 24 padded bit-rows (y0-10 .. y0+13) x 18 words
    __shared__ uint32_t sb[24 * RWORDS];
    const uint32_t* img = bits + (size_t)b * IMG_WORDS;
    for (int i = tid; i < 24 * RWORDS; i += 256)
        sb[i] = img[(size_t)(y0 + i / RWORDS) * RWORDS + (i % RWORDS)];
    __syncthreads();

    // thread's word pair: window for px x..x+7 needs row bits (x+22)..(x+49)
    const int lw = (x + 22) >> 5;
    const int s0 = (x + 22) & 31;
    // row for dy: sb[(wave + 10 + dy)*RWORDS + lw(+1)]
    const uint32_t* wrow = sb + wave * RWORDS + lw;

    uint32_t mind2[8];
#pragma unroll
    for (int i = 0; i < 8; ++i) mind2[i] = 1u << 20;

    // fold: for pixel i, c bit k = (fg at dx=+k) | (fg at dx=-k); sentinel at bit m+1
    // w32 bit j = row bit (x+22)+j; pixel i center at j = 10+i.
#define FOLD(K2, M, LO, HI) { \
        const uint32_t w32 = ALIGNBIT((HI), (LO), s0); \
        const uint32_t rv = __builtin_bitreverse32(w32); \
        _Pragma("unroll") \
        for (int i = 0; i < 8; ++i) { \
            uint32_t cc = (w32 >> (10 + i)) | (rv >> (21 - i)); \
            cc = (cc & ((1u << ((M) + 1)) - 1u)) | (1u << ((M) + 1)); \
            uint32_t dx = (uint32_t)__builtin_ctz(cc) & 31u; \
            uint32_t d2 = (uint32_t)(K2) + dx * dx; \
            mind2[i] = min(mind2[i], d2); \
        } }

#define PAIR(K, M) { \
        const uint32_t lo = wrow[(10 + (K)) * RWORDS]     | wrow[(10 - (K)) * RWORDS]; \
        const uint32_t hi = wrow[(10 + (K)) * RWORDS + 1] | wrow[(10 - (K)) * RWORDS + 1]; \
        FOLD((K) * (K), (M), lo, hi) }

#define CHECK(K) { \
        const uint32_t mx = max(max(max(mind2[0], mind2[1]), max(mind2[2], mind2[3])), \
                                max(max(mind2[4], mind2[5]), max(mind2[6], mind2[7]))); \
        if (__all(mx <= (uint32_t)((K) * (K)))) goto dt_done; }

    {   // center row (dy = 0)
        const uint32_t lo = wrow[10 * RWORDS];
        const uint32_t hi = wrow[10 * RWORDS + 1];
        FOLD(0, 10, lo, hi)
    }
    CHECK(1)
    PAIR(1, 9)  CHECK(2)
    PAIR(2, 9)  CHECK(3)
    PAIR(3, 9)  CHECK(4)
    PAIR(4, 9)  CHECK(5)
    PAIR(5, 8)  CHECK(6)
    PAIR(6, 8)  CHECK(7)
    PAIR(7, 7)  CHECK(8)
    PAIR(8, 6)  CHECK(9)
    PAIR(9, 4)  CHECK(10)
    PAIR(10, 0)
dt_done:;

    // ---- per-pixel loss terms ----
    const size_t base = ((size_t)b * NH + y) * NW + x;
    const float4* pp = (const float4*)(pred + base);
    const float4* tp = (const float4*)(targ + base);
    const float4 p0 = pp[0], p1 = pp[1];
    const float4 t0 = tp[0], t1 = tp[1];
    float pv[8] = {p0.x, p0.y, p0.z, p0.w, p1.x, p1.y, p1.z, p1.w};
    float tv[8] = {t0.x, t0.y, t0.z, t0.w, t1.x, t1.y, t1.z, t1.w};

    float s[8] = {0, 0, 0, 0, 0, 0, 0, 0};
#pragma unroll
    for (int i = 0; i < 8; ++i) {
        const float xv = pv[i], t = tv[i];
        const float ax = fabsf(xv);
        const float e  = __expf(-ax);
        const float L  = __logf(1.0f + e);                 // log1p(exp(-|x|))
        const float r  = __builtin_amdgcn_rcpf(1.0f + e);
        const float p  = (xv >= 0.0f) ? r : e * r;         // sigmoid(x)
        const float pc = fminf(fmaxf(p, 1e-7f), 0.99999988f);
        const float tb = (t > 0.5f) ? 1.0f : 0.0f;
        const float minx = fminf(xv, 0.0f), maxx = fmaxf(xv, 0.0f);
        // log(pc) = clamp(log sigmoid, bounds); log sigmoid = min(x,0) - L
        const float logpc   = fminf(fmaxf(minx - L, -16.118096f), -1.1920929e-7f);
        const float log1mpc = fminf(fmaxf(-maxx - L, -16.118096f), -1.1920929e-7f);
        const float bce = maxx - xv * t + L;
        const float dist = (mind2[i] > 100u) ? 10.0f : __fsqrt_rn((float)mind2[i]);
        const float bce_p = -(t * logpc + (1.0f - t) * log1mpc);
        s[0] += pc * t;
        s[1] += pc;
        s[2] += t;
        s[3] += bce;
        s[4] += dist * fabsf(pc - tb);
        s[5] += tb;
        s[6] += tb * bce_p;
        s[7] += (1.0f - tb) * bce_p;
    }

    // ---- block reduction: wave shuffle -> LDS -> 8 atomics/block ----
#pragma unroll
    for (int k = 0; k < 8; ++k) {
#pragma unroll
        for (int off = 32; off > 0; off >>= 1)
            s[k] += __shfl_down(s[k], off, 64);
    }
    __shared__ float red[4][8];
    if (lane == 0) {
#pragma unroll
        for (int k = 0; k < 8; ++k) red[wave][k] = s[k];
    }
    __syncthreads();
    if (tid < 8) {
        const float sum = red[0][tid] + red[1][tid] + red[2][tid] + red[3][tid];
        atomicAdd(&partials[b * 8 + tid], sum);
    }
}

// ---------------- kernel C: per-sample combine + batch mean ----------------
__global__ __launch_bounds__(64) void finalize(const float* __restrict__ partials,
                                               const int* __restrict__ task_ids,
                                               float* __restrict__ out) {
    const int b = threadIdx.x;  // 64 samples, one wave
    const float Nf = (float)NPIX;
    const float inter = partials[b * 8 + 0];
    const float spc   = partials[b * 8 + 1];
    const float st    = partials[b * 8 + 2];
    const float sbce  = partials[b * 8 + 3];
    const float sbdry = partials[b * 8 + 4];
    const float sfg   = partials[b * 8 + 5];
    const float sfgb  = partials[b * 8 + 6];
    const float sbgb  = partials[b * 8 + 7];

    const float dice = 1.0f - (2.0f * inter + 1e-5f) / (spc + st + 1e-5f);
    const float base = dice + sbce / Nf;
    const float bdry = sbdry / Nf;
    const float bgc  = Nf - sfg;
    const float fgw  = fminf(fmaxf(bgc / (sfg + 1e-7f), 1.0f), 10.0f);
    float fgl = (fgw * sfgb + sbgb) / Nf;
    if (sfg == 0.0f) fgl = 0.0f;

    const int t = task_ids[b];
    const float BW[3]  = {1.0f, 1.0f, 1.0f};
    const float BDW[3] = {2.0f, 3.0f, 5.0f};
    const float FW[3]  = {1.0f, 1.5f, 3.0f};
    float per = BW[t] * base + BDW[t] * bdry + FW[t] * fgl;

#pragma unroll
    for (int off = 32; off > 0; off >>= 1)
        per += __shfl_down(per, off, 64);
    if (b == 0) out[0] = per * (1.0f / 64.0f);
}

extern "C" void kernel_launch(void* const* d_in, const int* in_sizes, int n_in,
                              void* d_out, int out_size, void* d_ws, size_t ws_size,
                              hipStream_t stream) {
    const float* pred     = (const float*)d_in[0];
    const float* targ     = (const float*)d_in[1];
    const int*   task_ids = (const int*)d_in[2];
    float* out = (float*)d_out;

    // ws layout: [0,2KB) per-sample partials, [4KB, 4KB+2.45MB) bitmask
    float* partials = (float*)d_ws;
    uint32_t* bits = (uint32_t*)((char*)d_ws + 4096);

    // zero partials + entire bitmask (covers pad rows/words) in one memset
    hipMemsetAsync(d_ws, 0, 4096 + (size_t)NB * IMG_WORDS * sizeof(uint32_t), stream);
    build_bits<<<dim3(NH / 4, NB), 256, 0, stream>>>(targ, bits);
    main_loss<<<dim3(NH / 4, NB), 256, 0, stream>>>(pred, targ, bits, partials);
    finalize<<<1, 64, 0, stream>>>(partials, task_ids, out);
}